// Round 1
// baseline (165.058 us; speedup 1.0000x reference)
//
#include <hip/hip_runtime.h>

// SRL embeddings, fused single kernel.
// Shapes fixed by the problem: B=16,S=16,L=128,D=768,A=8,T=5.
// One block per (b,s). 768 threads = (r in 0..3 l-phase) x (q in 0..191 float4 col).
// - Pooling: sum hidden[b,s,l<len,:] / len (masks are prefix masks; len via
//   __syncthreads_count on the staged mask values -> masked rows never loaded).
// - Arg embeddings: only the LAST valid t per (b,s,a) is gathered by the
//   reference, so each of the 24 slots needs one token's match list
//   (expected ~1 row) and a mean over those rows (L2 hits).

namespace {
constexpr int Bc = 16, Sc = 16, Lc = 128, Dc = 768, Ac = 8, Tc = 5;
constexpr int NF4   = Dc / 4;          // 192 float4 per row
constexpr int NSLOT = 3 * Ac;          // 24 arg slots (pred, arg0, arg1) x 8
constexpr int BLOCK = 768;             // 12 waves
constexpr int OUT1  = Bc * Sc * NF4;        // sentence output, float4 units
constexpr int OUTG  = Bc * Sc * Ac * NF4;   // per-arg-type output, float4 units
}

__global__ __launch_bounds__(BLOCK) void srl_fused(
    const float4* __restrict__ hid,
    const int*    __restrict__ sids,
    const int*    __restrict__ amask,
    const int*    __restrict__ pids,
    const int*    __restrict__ a0ids,
    const int*    __restrict__ a1ids,
    float4*       __restrict__ out)
{
  const int bs  = blockIdx.x;
  const int tid = threadIdx.x;
  const int q   = tid % NF4;   // float4 column
  const int r   = tid / NF4;   // l-phase 0..3 (uniform per wave: 192 = 3 waves)

  __shared__ int    sid[Lc];
  __shared__ short  slist[NSLOT][Lc];
  __shared__ int    scnt[NSLOT];
  __shared__ float4 red[BLOCK];

  // Phase A: stage sentence ids; count mask ones (prefix length) in the same
  // barrier via __syncthreads_count — no extra sync, no LDS mask copy.
  int mval = 0;
  if (tid < Lc) {
    sid[tid] = sids[bs * Lc + tid];
    mval     = amask[bs * Lc + tid];
  }
  const int len = __syncthreads_count(mval != 0);

  const float4* __restrict__ hrow = hid + (size_t)bs * Lc * NF4;

  // Phase B (lanes 0..23 of wave 0, overlapped with pooling on other waves):
  // per slot, count matches for all 5 tokens in one sid scan, pick the LAST
  // valid t (tok!=0 && cnt>0), then build its match list.
  if (tid < NSLOT) {
    const int g = tid / Ac, a = tid % Ac;
    const int* ids = (g == 0 ? pids : (g == 1 ? a0ids : a1ids)) + (bs * Ac + a) * Tc;
    int tok[Tc], cnt[Tc];
#pragma unroll
    for (int t = 0; t < Tc; ++t) { tok[t] = ids[t]; cnt[t] = 0; }
    for (int l = 0; l < Lc; ++l) {
      const int v = sid[l];   // broadcast read (all 24 lanes same address)
#pragma unroll
      for (int t = 0; t < Tc; ++t) cnt[t] += (v == tok[t]) ? 1 : 0;
    }
    int sel = 0, n = 0;
#pragma unroll
    for (int t = Tc - 1; t >= 0; --t) {
      if (n == 0 && tok[t] != 0 && cnt[t] > 0) { sel = tok[t]; n = cnt[t]; }
    }
    scnt[tid] = n;
    if (n > 0) {
      int k = 0;
      for (int l = 0; l < Lc; ++l)
        if (sid[l] == sel) slist[tid][k++] = (short)l;
    }
  }

  // Phase C: pooling partial sums over the valid prefix, l-split by r.
  float ax = 0.f, ay = 0.f, az = 0.f, aw = 0.f;
  for (int l = r; l < len; l += 4) {
    const float4 v = hrow[l * NF4 + q];
    ax += v.x; ay += v.y; az += v.z; aw += v.w;
  }
  red[tid] = make_float4(ax, ay, az, aw);
  __syncthreads();   // red ready; also publishes scnt/slist for Phase D

  // Phase C2: reduce the 4 l-phases, divide by len, write sentence embedding.
  if (tid < NF4) {
    const float4 s0 = red[q];
    const float4 s1 = red[NF4 + q];
    const float4 s2 = red[2 * NF4 + q];
    const float4 s3 = red[3 * NF4 + q];
    const float inv = 1.0f / (float)(len > 0 ? len : 1);
    float4 o;
    o.x = (s0.x + s1.x + s2.x + s3.x) * inv;
    o.y = (s0.y + s1.y + s2.y + s3.y) * inv;
    o.z = (s0.z + s1.z + s2.z + s3.z) * inv;
    o.w = (s0.w + s1.w + s2.w + s3.w) * inv;
    out[bs * NF4 + q] = o;
  }

  // Phase D: arg embeddings. Each wave has uniform r -> uniform slot j ->
  // uniform branch; match-row loads hit L2 (tile just streamed in Phase C).
  for (int j = r; j < NSLOT; j += 4) {
    const int n = scnt[j];
    float ox = 0.f, oy = 0.f, oz = 0.f, ow = 0.f;
    if (n > 0) {
      for (int i = 0; i < n; ++i) {
        const int l = (int)slist[j][i];   // broadcast read
        const float4 v = hrow[l * NF4 + q];
        ox += v.x; oy += v.y; oz += v.z; ow += v.w;
      }
      const float inv = 1.0f / (float)n;
      ox *= inv; oy *= inv; oz *= inv; ow *= inv;
    }
    const int g = j / Ac, a = j % Ac;
    out[OUT1 + g * OUTG + (bs * Ac + a) * NF4 + q] = make_float4(ox, oy, oz, ow);
  }
}

extern "C" void kernel_launch(void* const* d_in, const int* in_sizes, int n_in,
                              void* d_out, int out_size, void* d_ws, size_t ws_size,
                              hipStream_t stream) {
  const float4* hid   = (const float4*)d_in[0];
  const int*    sids  = (const int*)d_in[1];
  const int*    amask = (const int*)d_in[2];
  const int*    pids  = (const int*)d_in[3];
  const int*    a0ids = (const int*)d_in[4];
  const int*    a1ids = (const int*)d_in[5];
  float4*       out   = (float4*)d_out;

  srl_fused<<<dim3(Bc * Sc), dim3(BLOCK), 0, stream>>>(
      hid, sids, amask, pids, a0ids, a1ids, out);
}

// Round 2
// 159.000 us; speedup vs baseline: 1.0381x; 1.0381x over previous
//
#include <hip/hip_runtime.h>

// SRL embeddings, fused single kernel — R2: D-split for occupancy.
// Shapes fixed: B=16,S=16,L=128,D=768,A=8,T=5.
// Grid = (6 chunks, 256 (b,s)) = 1536 blocks of 256 threads (~6 blocks/CU,
// 24 waves/CU vs R1's 12). Each block handles 32 float4 columns (512 B-aligned
// disjoint slice of each 3 KB row): thread = (r = l-phase 0..7, q = col 0..31).
// - Pooling: sum hidden[b,s,l<len, chunk]/len; masks are prefix masks, len via
//   __syncthreads_count -> masked rows never loaded.
// - Arg embeddings: reference keeps only the LAST valid t per (b,s,a); each of
//   24 slots needs one token's match list (~1 row) re-read from L1/L2 (same
//   columns this block just streamed).

namespace {
constexpr int Bc = 16, Sc = 16, Lc = 128, Dc = 768, Ac = 8, Tc = 5;
constexpr int NF4    = Dc / 4;          // 192 float4 per row
constexpr int CHUNK  = 32;              // float4 columns per block
constexpr int NCHUNK = NF4 / CHUNK;     // 6
constexpr int BLOCK  = 256;             // 4 waves
constexpr int RP     = BLOCK / CHUNK;   // 8 l-phases
constexpr int NSLOT  = 3 * Ac;          // 24 arg slots
constexpr int OUT1   = Bc * Sc * NF4;       // sentence output, float4 units
constexpr int OUTG   = Bc * Sc * Ac * NF4;  // per-arg-type output, float4 units
}

__global__ __launch_bounds__(BLOCK) void srl_fused(
    const float4* __restrict__ hid,
    const int*    __restrict__ sids,
    const int*    __restrict__ amask,
    const int*    __restrict__ pids,
    const int*    __restrict__ a0ids,
    const int*    __restrict__ a1ids,
    float4*       __restrict__ out)
{
  const int c   = blockIdx.x;           // column chunk 0..5
  const int bs  = blockIdx.y;           // (b,s) 0..255
  const int tid = threadIdx.x;
  const int q   = tid & (CHUNK - 1);    // float4 column within chunk
  const int r   = tid >> 5;             // l-phase 0..7

  __shared__ int    sid[Lc];
  __shared__ short  slist[NSLOT][Lc];
  __shared__ int    scnt[NSLOT];
  __shared__ float4 red[BLOCK];

  // Phase A: stage sentence ids; prefix length via __syncthreads_count.
  int mval = 0;
  if (tid < Lc) {
    sid[tid] = sids[bs * Lc + tid];
    mval     = amask[bs * Lc + tid];
  }
  const int len = __syncthreads_count(mval != 0);

  const float4* __restrict__ hrow = hid + (size_t)bs * Lc * NF4 + c * CHUNK;

  // Phase B (lanes 0..23 of wave 0, overlapped with pooling on other waves):
  // count matches for all 5 tokens in one sid scan, pick LAST valid t
  // (tok!=0 && cnt>0), build its match list.
  if (tid < NSLOT) {
    const int g = tid / Ac, a = tid % Ac;
    const int* ids = (g == 0 ? pids : (g == 1 ? a0ids : a1ids)) + (bs * Ac + a) * Tc;
    int tok[Tc], cnt[Tc];
#pragma unroll
    for (int t = 0; t < Tc; ++t) { tok[t] = ids[t]; cnt[t] = 0; }
    for (int l = 0; l < Lc; ++l) {
      const int v = sid[l];   // broadcast read
#pragma unroll
      for (int t = 0; t < Tc; ++t) cnt[t] += (v == tok[t]) ? 1 : 0;
    }
    int sel = 0, n = 0;
#pragma unroll
    for (int t = Tc - 1; t >= 0; --t) {
      if (n == 0 && tok[t] != 0 && cnt[t] > 0) { sel = tok[t]; n = cnt[t]; }
    }
    scnt[tid] = n;
    if (n > 0) {
      int k = 0;
      for (int l = 0; l < Lc; ++l)
        if (sid[l] == sel) slist[tid][k++] = (short)l;
    }
  }

  // Phase C: pooling partial sums over the valid prefix, l-split by r.
  float ax = 0.f, ay = 0.f, az = 0.f, aw = 0.f;
#pragma unroll 4
  for (int l = r; l < len; l += RP) {
    const float4 v = hrow[l * NF4 + q];
    ax += v.x; ay += v.y; az += v.z; aw += v.w;
  }
  red[tid] = make_float4(ax, ay, az, aw);
  __syncthreads();   // red ready; also publishes scnt/slist for Phase D

  // Phase C2: reduce the 8 l-phases, divide by len, write sentence embedding.
  if (tid < CHUNK) {
    float4 s = red[q];
#pragma unroll
    for (int p = 1; p < RP; ++p) {
      const float4 t = red[p * CHUNK + q];
      s.x += t.x; s.y += t.y; s.z += t.z; s.w += t.w;
    }
    const float inv = 1.0f / (float)(len > 0 ? len : 1);
    s.x *= inv; s.y *= inv; s.z *= inv; s.w *= inv;
    out[bs * NF4 + c * CHUNK + q] = s;
  }

  // Phase D: arg embeddings. 3 slots per l-phase; match rows hit L1/L2
  // (same columns streamed in Phase C).
  for (int j = r; j < NSLOT; j += RP) {
    const int n = scnt[j];
    float ox = 0.f, oy = 0.f, oz = 0.f, ow = 0.f;
    if (n > 0) {
      for (int i = 0; i < n; ++i) {
        const int l = (int)slist[j][i];   // broadcast read
        const float4 v = hrow[l * NF4 + q];
        ox += v.x; oy += v.y; oz += v.z; ow += v.w;
      }
      const float inv = 1.0f / (float)n;
      ox *= inv; oy *= inv; oz *= inv; ow *= inv;
    }
    const int g = j / Ac, a = j % Ac;
    out[OUT1 + g * OUTG + (bs * Ac + a) * NF4 + c * CHUNK + q] =
        make_float4(ox, oy, oz, ow);
  }
}

extern "C" void kernel_launch(void* const* d_in, const int* in_sizes, int n_in,
                              void* d_out, int out_size, void* d_ws, size_t ws_size,
                              hipStream_t stream) {
  const float4* hid   = (const float4*)d_in[0];
  const int*    sids  = (const int*)d_in[1];
  const int*    amask = (const int*)d_in[2];
  const int*    pids  = (const int*)d_in[3];
  const int*    a0ids = (const int*)d_in[4];
  const int*    a1ids = (const int*)d_in[5];
  float4*       out   = (float4*)d_out;

  srl_fused<<<dim3(NCHUNK, Bc * Sc), dim3(BLOCK), 0, stream>>>(
      hid, sids, amask, pids, a0ids, a1ids, out);
}